// Round 6
// baseline (455.801 us; speedup 1.0000x reference)
//
#include <hip/hip_runtime.h>
#include <stdint.h>

// Problem constants
#define BATCH 2
#define SEQ   2048
#define NH    16
#define DH    128
#define DM    2048      // NH*DH
#define NQKV  6144      // 3*DM
#define MROWS 4096      // BATCH*SEQ

typedef __bf16 bf16x8 __attribute__((ext_vector_type(8)));
typedef float  f32x4  __attribute__((ext_vector_type(4)));

#define FENCE() __asm__ __volatile__("" ::: "memory")

__device__ __forceinline__ void gl_lds16(const void* g, void* l) {
  __builtin_amdgcn_global_load_lds(
      (const __attribute__((address_space(1))) void*)g,
      (__attribute__((address_space(3))) void*)l, 16, 0, 0);
}

// fp32 -> bf16 (RNE)
__device__ __forceinline__ unsigned short f2bf(float f) {
  uint32_t u = __builtin_bit_cast(uint32_t, f);
  return (unsigned short)((u + 0x7FFFu + ((u >> 16) & 1u)) >> 16);
}

// DPP row_ror reduction within each 16-lane row (VALU pipe, no LDS).
template <int N>
__device__ __forceinline__ float dpp_ror(float x) {
  int r = __builtin_amdgcn_update_dpp(__builtin_bit_cast(int, x),
                                      __builtin_bit_cast(int, x),
                                      0x120 | N, 0xF, 0xF, false);
  return __builtin_bit_cast(float, r);
}
__device__ __forceinline__ float red16_max(float x) {
  x = fmaxf(x, dpp_ror<1>(x)); x = fmaxf(x, dpp_ror<2>(x));
  x = fmaxf(x, dpp_ror<4>(x)); x = fmaxf(x, dpp_ror<8>(x));
  return x;
}
__device__ __forceinline__ float red16_sum(float x) {
  x += dpp_ror<1>(x); x += dpp_ror<2>(x);
  x += dpp_ror<4>(x); x += dpp_ror<8>(x);
  return x;
}

// ---------------- prep kernels ----------------
__global__ void convert_x_kernel(const float* __restrict__ in,
                                 unsigned short* __restrict__ out) {
  int i = blockIdx.x * 256 + threadIdx.x;          // one float4 per thread
  float4 v = ((const float4*)in)[i];
  uint32_t lo = (uint32_t)f2bf(v.x) | ((uint32_t)f2bf(v.y) << 16);
  uint32_t hi = (uint32_t)f2bf(v.z) | ((uint32_t)f2bf(v.w) << 16);
  ((uint2*)out)[i] = make_uint2(lo, hi);
}

// in fp32 [K,N] row-major -> out bf16 [N,K] row-major
__global__ void transpose_w_kernel(const float* __restrict__ in,
                                   unsigned short* __restrict__ out,
                                   int K, int N) {
  __shared__ float tile[32][33];
  const int tx = threadIdx.x, ty = threadIdx.y;    // 32 x 8
  const int n0 = blockIdx.x * 32, k0 = blockIdx.y * 32;
  #pragma unroll
  for (int i = 0; i < 32; i += 8)
    tile[ty + i][tx] = in[(size_t)(k0 + ty + i) * N + n0 + tx];
  __syncthreads();
  #pragma unroll
  for (int i = 0; i < 32; i += 8)
    out[(size_t)(n0 + ty + i) * K + k0 + tx] = f2bf(tile[tx][ty + i]);
}

// ---------------- QKV GEMM (m97 gemm_bt structure) ----------------
__global__ void qkv_gemm_kernel(const unsigned short* __restrict__ A,
                                const unsigned short* __restrict__ Bt,
                                const float* __restrict__ bias,
                                unsigned short* __restrict__ Qb,
                                unsigned short* __restrict__ Kb,
                                unsigned short* __restrict__ Vtb) {
  __shared__ alignas(16) unsigned short As[128 * 32];
  __shared__ alignas(16) unsigned short Bs[128 * 32];
  const int tid = threadIdx.x;
  const int lane = tid & 63, wave = tid >> 6;
  const int wm = wave >> 1, wn = wave & 1;
  const int quad = lane >> 4, l15 = lane & 15;
  const int bm = blockIdx.x, bn = blockIdx.y;
  const int K = DM;

  f32x4 acc[4][4];
  #pragma unroll
  for (int i = 0; i < 4; ++i)
    #pragma unroll
    for (int j = 0; j < 4; ++j) acc[i][j] = (f32x4){0.f, 0.f, 0.f, 0.f};

  const unsigned short* Ag = A + (size_t)(bm * 128 + (tid >> 2)) * K + (tid & 3) * 8;
  const unsigned short* Bg = Bt + (size_t)(bn * 128 + (tid >> 2)) * K + (tid & 3) * 8;

  for (int kt = 0; kt < K / 32; ++kt) {
    gl_lds16(Ag + kt * 32,                  As + tid * 8);
    gl_lds16(Ag + (size_t)64 * K + kt * 32, As + 2048 + tid * 8);
    gl_lds16(Bg + kt * 32,                  Bs + tid * 8);
    gl_lds16(Bg + (size_t)64 * K + kt * 32, Bs + 2048 + tid * 8);
    __syncthreads();
    bf16x8 af[4], bfr[4];
    #pragma unroll
    for (int mi = 0; mi < 4; ++mi)
      af[mi] = *(const bf16x8*)(As + (wm * 64 + mi * 16 + l15) * 32 + quad * 8);
    #pragma unroll
    for (int ni = 0; ni < 4; ++ni)
      bfr[ni] = *(const bf16x8*)(Bs + (wn * 64 + ni * 16 + l15) * 32 + quad * 8);
    #pragma unroll
    for (int mi = 0; mi < 4; ++mi)
      #pragma unroll
      for (int ni = 0; ni < 4; ++ni)
        acc[mi][ni] = __builtin_amdgcn_mfma_f32_16x16x32_bf16(af[mi], bfr[ni], acc[mi][ni], 0, 0, 0);
    __syncthreads();
  }

  // epilogue: C/D layout col=lane&15, row=quad*4+reg [verified m89/m91]
  #pragma unroll
  for (int mi = 0; mi < 4; ++mi) {
    #pragma unroll
    for (int ni = 0; ni < 4; ++ni) {
      const int grow0 = bm * 128 + wm * 64 + mi * 16 + quad * 4;
      const int gcol  = bn * 128 + wn * 64 + ni * 16 + l15;
      const float bv = bias[gcol];
      const int which = gcol >> 11;          // 0=Q 1=K 2=V
      const int rem = gcol & 2047;
      const int h = rem >> 7, d = rem & 127;
      #pragma unroll
      for (int r = 0; r < 4; ++r) {
        const int grow = grow0 + r;
        const int b = grow >> 11, s = grow & 2047;
        const int bh = b * NH + h;
        const unsigned short val = f2bf(acc[mi][ni][r] + bv);
        if (which == 0)      Qb[((size_t)bh * SEQ + s) * DH + d] = val;
        else if (which == 1) Kb[((size_t)bh * SEQ + s) * DH + d] = val;
        else                 // V^T TILED: [bh][kvtile=32][d=128][kv=64] — tile = contiguous 16KB
          Vtb[(((size_t)bh * 32 + (s >> 6)) * 128 + d) * 64 + (s & 63)] = val;
      }
    }
  }
}

// ---------------- flash attention (pipelined, spill-free, 2 blocks/CU) ----------------
// grid (16 qtiles, 32 bh), 256 threads; triangular work, longest-first.
// 512 blocks / 256 CUs with LDS 66KB + VGPR<=256 -> 2 blocks/CU co-resident:
// the second block's compute overlaps this block's barrier/staging stalls
// (R5's 256-block pairing gave 1 block/CU = nothing to overlap with).
#define PS_LD 72
__global__ __launch_bounds__(256, 2)
void attn_kernel(const unsigned short* __restrict__ Qb,   // [32,2048,128]
                 const unsigned short* __restrict__ Kb,   // [32,2048,128]
                 const unsigned short* __restrict__ Vtb,  // [32,32,128,64] tiled V^T
                 unsigned short* __restrict__ Ob) {       // [4096,2048]
  __shared__ alignas(16) unsigned short lds_all[33792];  // 66 KB
  unsigned short* Ks  = lds_all;           // [kv=64][d=128] swizzled, 16KB (single buf)
  unsigned short* Vs0 = lds_all + 8192;    // [d=128][kv=64] swizzled, 16KB
  unsigned short* Vs1 = lds_all + 16384;
  const int tid = threadIdx.x, lane = tid & 63, wave = tid >> 6;
  unsigned short* Ps = lds_all + 24576 + wave * (32 * PS_LD);
  const int quad = lane >> 4, l15 = lane & 15;
  const int bh = blockIdx.y;
  const int b = bh >> 4, h = bh & 15;
  const int qb = 15 - (int)blockIdx.x;     // longest blocks first
  const int q0 = qb * 128 + wave * 32;
  const float c = 0.08838834764831845f * 1.4426950408889634f; // 1/sqrt(128)*log2(e)

  const unsigned short* Kbase = Kb + (size_t)bh * SEQ * DH;
  const unsigned short* Vbase = Vtb + (size_t)bh * 32 * 8192;

  // staging helpers (4 gl_lds each = 16KB/block-tile)
  auto stage_k = [&](int kt) {
    const unsigned short* kg = Kbase + (size_t)kt * 64 * DH;
    #pragma unroll
    for (int r = 0; r < 4; ++r) {
      const int idx = r * 256 + tid;
      const int krow = idx >> 4, kchunk = (idx & 15) ^ (krow & 7);
      gl_lds16(kg + krow * DH + kchunk * 8, Ks + idx * 8);
    }
  };
  auto stage_v = [&](int kt, unsigned short* vs) {
    const unsigned short* vg = Vbase + (size_t)kt * 8192;
    #pragma unroll
    for (int r = 0; r < 4; ++r) {
      const int idx = r * 256 + tid;
      const int vrow = idx >> 3, vchunk = (idx & 7) ^ (vrow & 7);
      gl_lds16(vg + vrow * 64 + vchunk * 8, vs + idx * 8);
    }
  };

  // Q fragments in registers: A-layout m=lane&15, k=quad*8+j [m120]
  bf16x8 qf[2][4];
  #pragma unroll
  for (int mi = 0; mi < 2; ++mi)
    #pragma unroll
    for (int ds = 0; ds < 4; ++ds)
      qf[mi][ds] = *(const bf16x8*)(Qb + ((size_t)bh * SEQ + q0 + mi * 16 + l15) * DH + ds * 32 + quad * 8);

  f32x4 o[2][8];
  #pragma unroll
  for (int mi = 0; mi < 2; ++mi)
    #pragma unroll
    for (int di = 0; di < 8; ++di) o[mi][di] = (f32x4){0.f, 0.f, 0.f, 0.f};
  float m_i[2][4], l_i[2][4];
  #pragma unroll
  for (int mi = 0; mi < 2; ++mi)
    #pragma unroll
    for (int r = 0; r < 4; ++r) { m_i[mi][r] = -INFINITY; l_i[mi][r] = 0.f; }

  const int nkt = (qb + 1) * 2;   // 64-wide kv tiles (even, >=2)

  stage_v(0, Vs0);
  stage_k(0);
  __builtin_amdgcn_s_waitcnt(0x0F70);   // vmcnt(0)
  FENCE(); __builtin_amdgcn_s_barrier(); FENCE();

  for (int kt = 0; kt < nkt; ++kt) {
    unsigned short* Vcur = (kt & 1) ? Vs1 : Vs0;
    const bool more = (kt + 1 < nkt);
    if (more) stage_v(kt + 1, (kt & 1) ? Vs0 : Vs1);   // in flight during QK
    FENCE();

    // S = Q K^T from Ks
    f32x4 s_acc[2][4];
    #pragma unroll
    for (int mi = 0; mi < 2; ++mi)
      #pragma unroll
      for (int ni = 0; ni < 4; ++ni) s_acc[mi][ni] = (f32x4){0.f, 0.f, 0.f, 0.f};
    #pragma unroll
    for (int ds = 0; ds < 4; ++ds) {
      bf16x8 kf[4];
      #pragma unroll
      for (int ni = 0; ni < 4; ++ni) {
        const int krow = ni * 16 + l15;
        const int kc = (ds * 4 + quad) ^ (krow & 7);
        kf[ni] = *(const bf16x8*)(Ks + (krow * 16 + kc) * 8);
      }
      #pragma unroll
      for (int mi = 0; mi < 2; ++mi)
        #pragma unroll
        for (int ni = 0; ni < 4; ++ni)
          s_acc[mi][ni] = __builtin_amdgcn_mfma_f32_16x16x32_bf16(qf[mi][ds], kf[ni], s_acc[mi][ni], 0, 0, 0);
    }

    FENCE(); __builtin_amdgcn_s_barrier(); FENCE();  // all waves done reading Ks
    if (more) stage_k(kt + 1);                       // in flight during softmax+PV
    FENCE();

    // scale into 2^x domain (+ causal mask only on boundary tiles — wave-uniform)
    if (kt * 64 + 63 > q0) {
      #pragma unroll
      for (int mi = 0; mi < 2; ++mi)
        #pragma unroll
        for (int ni = 0; ni < 4; ++ni) {
          const int kcol = kt * 64 + ni * 16 + l15;
          #pragma unroll
          for (int r = 0; r < 4; ++r) {
            float v = s_acc[mi][ni][r] * c;
            const int qrow = q0 + mi * 16 + quad * 4 + r;
            if (kcol > qrow) v = -INFINITY;
            s_acc[mi][ni][r] = v;
          }
        }
    } else {
      #pragma unroll
      for (int mi = 0; mi < 2; ++mi)
        #pragma unroll
        for (int ni = 0; ni < 4; ++ni)
          #pragma unroll
          for (int r = 0; r < 4; ++r) s_acc[mi][ni][r] *= c;
    }

    // online softmax; row lives in its 16-lane group -> DPP rotate-reduce
    #pragma unroll
    for (int mi = 0; mi < 2; ++mi) {
      float rmax[4], alpha[4], rsum[4];
      #pragma unroll
      for (int r = 0; r < 4; ++r) {
        float m0 = fmaxf(fmaxf(s_acc[mi][0][r], s_acc[mi][1][r]),
                         fmaxf(s_acc[mi][2][r], s_acc[mi][3][r]));
        rmax[r] = red16_max(m0);
      }
      #pragma unroll
      for (int r = 0; r < 4; ++r) {
        const float mnew = fmaxf(m_i[mi][r], rmax[r]);
        alpha[r] = exp2f(m_i[mi][r] - mnew);   // exp2(-inf)=0 on first tile
        m_i[mi][r] = mnew;
      }
      #pragma unroll
      for (int r = 0; r < 4; ++r) {
        float s0 = 0.f;
        #pragma unroll
        for (int ni = 0; ni < 4; ++ni) {
          const float p = exp2f(s_acc[mi][ni][r] - m_i[mi][r]);
          s_acc[mi][ni][r] = p;
          s0 += p;
        }
        rsum[r] = red16_sum(s0);
      }
      #pragma unroll
      for (int r = 0; r < 4; ++r) l_i[mi][r] = l_i[mi][r] * alpha[r] + rsum[r];
      #pragma unroll
      for (int di = 0; di < 8; ++di)
        #pragma unroll
        for (int r = 0; r < 4; ++r) o[mi][di][r] *= alpha[r];
      // P: C-layout -> LDS (padded, per-wave private) -> A-layout [m120]
      #pragma unroll
      for (int ni = 0; ni < 4; ++ni)
        #pragma unroll
        for (int r = 0; r < 4; ++r)
          Ps[(mi * 16 + quad * 4 + r) * PS_LD + ni * 16 + l15] = f2bf(s_acc[mi][ni][r]);
    }
    FENCE();   // Ps ushort writes before bf16x8 reads (same-wave DS in-order)

    // O += P V from Vcur
    #pragma unroll
    for (int ks = 0; ks < 2; ++ks) {
      bf16x8 pf[2];
      #pragma unroll
      for (int mi = 0; mi < 2; ++mi)
        pf[mi] = *(const bf16x8*)(Ps + (mi * 16 + l15) * PS_LD + ks * 32 + quad * 8);
      #pragma unroll
      for (int di = 0; di < 8; ++di) {
        const int vrow = di * 16 + l15;
        const int vc = (ks * 4 + quad) ^ (vrow & 7);
        const bf16x8 vf = *(const bf16x8*)(Vcur + (vrow * 8 + vc) * 8);
        #pragma unroll
        for (int mi = 0; mi < 2; ++mi)
          o[mi][di] = __builtin_amdgcn_mfma_f32_16x16x32_bf16(pf[mi], vf, o[mi][di], 0, 0, 0);
      }
    }

    if (more) {
      __builtin_amdgcn_s_waitcnt(0x0F70);  // drain K(t+1)+V(t+1)
      FENCE(); __builtin_amdgcn_s_barrier(); FENCE();
    }
  }

  // ---- epilogue: normalize, transpose via LDS, coalesced 16B stores ----
  __syncthreads();   // all waves done with Vs/Ps before Osc overwrites lds_all
  {
    unsigned short* Osc = lds_all + wave * (32 * 136);   // max 17408 el < 33792
    #pragma unroll
    for (int mi = 0; mi < 2; ++mi) {
      float inv[4];
      #pragma unroll
      for (int r = 0; r < 4; ++r) inv[r] = 1.0f / l_i[mi][r];
      #pragma unroll
      for (int di = 0; di < 8; ++di)
        #pragma unroll
        for (int r = 0; r < 4; ++r)
          Osc[(mi * 16 + quad * 4 + r) * 136 + di * 16 + l15] = f2bf(o[mi][di][r] * inv[r]);
    }
    __syncthreads();                        // order writes before re-typed reads
    FENCE();
    #pragma unroll
    for (int rh = 0; rh < 2; ++rh)
      #pragma unroll
      for (int cg = 0; cg < 4; ++cg) {
        const int row = rh * 16 + (lane >> 2);
        const bf16x8 v8 = *(const bf16x8*)(Osc + row * 136 + cg * 32 + (lane & 3) * 8);
        *(bf16x8*)(Ob + ((size_t)(b * SEQ + q0 + row)) * DM + h * DH + cg * 32 + (lane & 3) * 8) = v8;
      }
  }
}

// ---------------- out projection GEMM ----------------
__global__ void out_gemm_kernel(const unsigned short* __restrict__ A,   // [4096,2048] bf16
                                const unsigned short* __restrict__ Bt,  // [2048,2048] bf16 (W_out^T)
                                const float* __restrict__ bias,
                                float* __restrict__ out) {
  __shared__ alignas(16) unsigned short As[128 * 32];
  __shared__ alignas(16) unsigned short Bs[128 * 32];
  const int tid = threadIdx.x;
  const int lane = tid & 63, wave = tid >> 6;
  const int wm = wave >> 1, wn = wave & 1;
  const int quad = lane >> 4, l15 = lane & 15;
  const int bm = blockIdx.x, bn = blockIdx.y;
  const int K = DM;

  f32x4 acc[4][4];
  #pragma unroll
  for (int i = 0; i < 4; ++i)
    #pragma unroll
    for (int j = 0; j < 4; ++j) acc[i][j] = (f32x4){0.f, 0.f, 0.f, 0.f};

  const unsigned short* Ag = A + (size_t)(bm * 128 + (tid >> 2)) * K + (tid & 3) * 8;
  const unsigned short* Bg = Bt + (size_t)(bn * 128 + (tid >> 2)) * K + (tid & 3) * 8;

  for (int kt = 0; kt < K / 32; ++kt) {
    gl_lds16(Ag + kt * 32,                  As + tid * 8);
    gl_lds16(Ag + (size_t)64 * K + kt * 32, As + 2048 + tid * 8);
    gl_lds16(Bg + kt * 32,                  Bs + tid * 8);
    gl_lds16(Bg + (size_t)64 * K + kt * 32, Bs + 2048 + tid * 8);
    __syncthreads();
    bf16x8 af[4], bfr[4];
    #pragma unroll
    for (int mi = 0; mi < 4; ++mi)
      af[mi] = *(const bf16x8*)(As + (wm * 64 + mi * 16 + l15) * 32 + quad * 8);
    #pragma unroll
    for (int ni = 0; ni < 4; ++ni)
      bfr[ni] = *(const bf16x8*)(Bs + (wn * 64 + ni * 16 + l15) * 32 + quad * 8);
    #pragma unroll
    for (int mi = 0; mi < 4; ++mi)
      #pragma unroll
      for (int ni = 0; ni < 4; ++ni)
        acc[mi][ni] = __builtin_amdgcn_mfma_f32_16x16x32_bf16(af[mi], bfr[ni], acc[mi][ni], 0, 0, 0);
    __syncthreads();
  }

  #pragma unroll
  for (int mi = 0; mi < 4; ++mi) {
    #pragma unroll
    for (int ni = 0; ni < 4; ++ni) {
      const int grow0 = bm * 128 + wm * 64 + mi * 16 + quad * 4;
      const int gcol  = bn * 128 + wn * 64 + ni * 16 + l15;
      const float bv = bias[gcol];
      #pragma unroll
      for (int r = 0; r < 4; ++r)
        out[(size_t)(grow0 + r) * DM + gcol] = acc[mi][ni][r] + bv;
    }
  }
}

// ---------------- launch ----------------
extern "C" void kernel_launch(void* const* d_in, const int* in_sizes, int n_in,
                              void* d_out, int out_size, void* d_ws, size_t ws_size,
                              hipStream_t stream) {
  const float* x     = (const float*)d_in[0];   // [2,2048,2048]
  const float* W_qkv = (const float*)d_in[1];   // [2048,6144]
  const float* b_qkv = (const float*)d_in[2];   // [6144]
  const float* W_out = (const float*)d_in[3];   // [2048,2048]
  const float* b_out = (const float*)d_in[4];   // [2048]
  float* out = (float*)d_out;                   // [4096,2048]

  char* ws = (char*)d_ws;
  unsigned short* xb    = (unsigned short*)(ws);                 // 16 MB  [4096,2048]
  unsigned short* WqkvT = (unsigned short*)(ws + 16777216ull);   // 24 MB  [6144,2048]
  unsigned short* WoutT = (unsigned short*)(ws + 41943040ull);   //  8 MB  [2048,2048]
  unsigned short* Qb    = (unsigned short*)(ws + 50331648ull);   // 16 MB  [32,2048,128]
  unsigned short* Kb    = (unsigned short*)(ws + 67108864ull);   // 16 MB  [32,2048,128]
  unsigned short* Vtb   = (unsigned short*)(ws + 83886080ull);   // 16 MB  [32,32,128,64] tiled
  unsigned short* attnb = (unsigned short*)(ws + 100663296ull);  // 16 MB  [4096,2048]

  convert_x_kernel<<<dim3(8192), dim3(256), 0, stream>>>(x, xb);
  transpose_w_kernel<<<dim3(192, 64), dim3(32, 8), 0, stream>>>(W_qkv, WqkvT, DM, NQKV);
  transpose_w_kernel<<<dim3(64, 64), dim3(32, 8), 0, stream>>>(W_out, WoutT, DM, DM);
  qkv_gemm_kernel<<<dim3(32, 48), dim3(256), 0, stream>>>(xb, WqkvT, b_qkv, Qb, Kb, Vtb);
  attn_kernel<<<dim3(16, 32), dim3(256), 0, stream>>>(Qb, Kb, Vtb, attnb);
  out_gemm_kernel<<<dim3(32, 16), dim3(256), 0, stream>>>(attnb, WoutT, b_out, out);
}

// Round 7
// 425.910 us; speedup vs baseline: 1.0702x; 1.0702x over previous
//
#include <hip/hip_runtime.h>
#include <stdint.h>

// Problem constants
#define BATCH 2
#define SEQ   2048
#define NH    16
#define DH    128
#define DM    2048      // NH*DH
#define NQKV  6144      // 3*DM
#define MROWS 4096      // BATCH*SEQ

typedef __bf16 bf16x8 __attribute__((ext_vector_type(8)));
typedef float  f32x4  __attribute__((ext_vector_type(4)));

#define FENCE() __asm__ __volatile__("" ::: "memory")

__device__ __forceinline__ void gl_lds16(const void* g, void* l) {
  __builtin_amdgcn_global_load_lds(
      (const __attribute__((address_space(1))) void*)g,
      (__attribute__((address_space(3))) void*)l, 16, 0, 0);
}

// fp32 -> bf16 (RNE)
__device__ __forceinline__ unsigned short f2bf(float f) {
  uint32_t u = __builtin_bit_cast(uint32_t, f);
  return (unsigned short)((u + 0x7FFFu + ((u >> 16) & 1u)) >> 16);
}

// DPP row_ror reduction within each 16-lane row (VALU pipe, no LDS).
template <int N>
__device__ __forceinline__ float dpp_ror(float x) {
  int r = __builtin_amdgcn_update_dpp(__builtin_bit_cast(int, x),
                                      __builtin_bit_cast(int, x),
                                      0x120 | N, 0xF, 0xF, false);
  return __builtin_bit_cast(float, r);
}
__device__ __forceinline__ float red16_max(float x) {
  x = fmaxf(x, dpp_ror<1>(x)); x = fmaxf(x, dpp_ror<2>(x));
  x = fmaxf(x, dpp_ror<4>(x)); x = fmaxf(x, dpp_ror<8>(x));
  return x;
}
__device__ __forceinline__ float red16_sum(float x) {
  x += dpp_ror<1>(x); x += dpp_ror<2>(x);
  x += dpp_ror<4>(x); x += dpp_ror<8>(x);
  return x;
}

// ---------------- merged prep kernel ----------------
// blocks [0,8192): convert x fp32->bf16 (float4/thread)
// blocks [8192,20480): transpose W_qkv [2048,6144] -> bf16 [6144,2048]
// blocks [20480,24576): transpose W_out [2048,2048] -> bf16 [2048,2048]
__global__ void prep_kernel(const float* __restrict__ x,
                            const float* __restrict__ W_qkv,
                            const float* __restrict__ W_out,
                            unsigned short* __restrict__ xb,
                            unsigned short* __restrict__ WqkvT,
                            unsigned short* __restrict__ WoutT) {
  __shared__ float tile[32][33];
  const int bid = blockIdx.x, tid = threadIdx.x;
  if (bid < 8192) {
    const int i = bid * 256 + tid;
    float4 v = ((const float4*)x)[i];
    uint32_t lo = (uint32_t)f2bf(v.x) | ((uint32_t)f2bf(v.y) << 16);
    uint32_t hi = (uint32_t)f2bf(v.z) | ((uint32_t)f2bf(v.w) << 16);
    ((uint2*)xb)[i] = make_uint2(lo, hi);
    return;
  }
  const float* in; unsigned short* out; int K, N, bx, by;
  if (bid < 20480) { const int rel = bid - 8192;  in = W_qkv; out = WqkvT; K = DM; N = NQKV; bx = rel % 192; by = rel / 192; }
  else             { const int rel = bid - 20480; in = W_out; out = WoutT; K = DM; N = DM;   bx = rel % 64;  by = rel / 64; }
  const int tx = tid & 31, ty = tid >> 5;          // 32 x 8
  const int n0 = bx * 32, k0 = by * 32;
  #pragma unroll
  for (int i = 0; i < 32; i += 8)
    tile[ty + i][tx] = in[(size_t)(k0 + ty + i) * N + n0 + tx];
  __syncthreads();
  #pragma unroll
  for (int i = 0; i < 32; i += 8)
    out[(size_t)(n0 + ty + i) * K + k0 + tx] = f2bf(tile[tx][ty + i]);
}

// ---------------- QKV GEMM (m97 structure, BK=64, swizzled LDS) ----------------
// BK=64 halves the barrier count (32 vs 64 K-iters). Row stride 64el=128B would be
// 16-way bank-aliased, so chunks are XOR-swizzled: phys_chunk = chunk ^ (row&7)
// (same verified pattern as attn staging). Staging stays lane-contiguous 16B.
__global__ void qkv_gemm_kernel(const unsigned short* __restrict__ A,
                                const unsigned short* __restrict__ Bt,
                                const float* __restrict__ bias,
                                unsigned short* __restrict__ Qb,
                                unsigned short* __restrict__ Kb,
                                unsigned short* __restrict__ Vtb) {
  __shared__ alignas(16) unsigned short As[128 * 64];   // 16KB
  __shared__ alignas(16) unsigned short Bs[128 * 64];   // 16KB
  const int tid = threadIdx.x;
  const int lane = tid & 63, wave = tid >> 6;
  const int wm = wave >> 1, wn = wave & 1;
  const int quad = lane >> 4, l15 = lane & 15;
  const int bm = blockIdx.x, bn = blockIdx.y;
  const int K = DM;

  f32x4 acc[4][4];
  #pragma unroll
  for (int i = 0; i < 4; ++i)
    #pragma unroll
    for (int j = 0; j < 4; ++j) acc[i][j] = (f32x4){0.f, 0.f, 0.f, 0.f};

  // staging source addresses: thread handles 4 chunks of each tile
  // idx = r*256+tid; row = idx>>3 (0..127), chunk = (idx&7)^(row&7)
  for (int kt = 0; kt < K / 64; ++kt) {
    #pragma unroll
    for (int r = 0; r < 4; ++r) {
      const int idx = r * 256 + tid;
      const int row = idx >> 3, chunk = (idx & 7) ^ (row & 7);
      gl_lds16(A  + (size_t)(bm * 128 + row) * K + kt * 64 + chunk * 8, As + idx * 8);
      gl_lds16(Bt + (size_t)(bn * 128 + row) * K + kt * 64 + chunk * 8, Bs + idx * 8);
    }
    __syncthreads();
    #pragma unroll
    for (int ds = 0; ds < 2; ++ds) {      // two K=32 steps within the BK=64 tile
      bf16x8 af[4], bfr[4];
      #pragma unroll
      for (int mi = 0; mi < 4; ++mi) {
        const int row = wm * 64 + mi * 16 + l15;
        const int c = (ds * 4 + quad) ^ (row & 7);
        af[mi] = *(const bf16x8*)(As + (row * 8 + c) * 8);
      }
      #pragma unroll
      for (int ni = 0; ni < 4; ++ni) {
        const int row = wn * 64 + ni * 16 + l15;
        const int c = (ds * 4 + quad) ^ (row & 7);
        bfr[ni] = *(const bf16x8*)(Bs + (row * 8 + c) * 8);
      }
      #pragma unroll
      for (int mi = 0; mi < 4; ++mi)
        #pragma unroll
        for (int ni = 0; ni < 4; ++ni)
          acc[mi][ni] = __builtin_amdgcn_mfma_f32_16x16x32_bf16(af[mi], bfr[ni], acc[mi][ni], 0, 0, 0);
    }
    __syncthreads();
  }

  // epilogue: C/D layout col=lane&15, row=quad*4+reg [verified m89/m91]
  #pragma unroll
  for (int mi = 0; mi < 4; ++mi) {
    #pragma unroll
    for (int ni = 0; ni < 4; ++ni) {
      const int grow0 = bm * 128 + wm * 64 + mi * 16 + quad * 4;
      const int gcol  = bn * 128 + wn * 64 + ni * 16 + l15;
      const float bv = bias[gcol];
      const int which = gcol >> 11;          // 0=Q 1=K 2=V
      const int rem = gcol & 2047;
      const int h = rem >> 7, d = rem & 127;
      #pragma unroll
      for (int r = 0; r < 4; ++r) {
        const int grow = grow0 + r;
        const int b = grow >> 11, s = grow & 2047;
        const int bh = b * NH + h;
        const unsigned short val = f2bf(acc[mi][ni][r] + bv);
        if (which == 0)      Qb[((size_t)bh * SEQ + s) * DH + d] = val;
        else if (which == 1) Kb[((size_t)bh * SEQ + s) * DH + d] = val;
        else                 // V^T TILED: [bh][kvtile=32][d=128][kv=64] — tile = contiguous 16KB
          Vtb[(((size_t)bh * 32 + (s >> 6)) * 128 + d) * 64 + (s & 63)] = val;
      }
    }
  }
}

// ---------------- flash attention (R5 structure: paired q-tiles, spill-free) ----------------
// grid (8 qtile-pairs, 32 bh), 256 threads. Block p processes qb=15-p then qb=p:
// uniform 34 kv-iters/block. __launch_bounds__(256,2) caps VGPR at 256 -> no spills.
#define PS_LD 72
__global__ __launch_bounds__(256, 2)
void attn_kernel(const unsigned short* __restrict__ Qb,   // [32,2048,128]
                 const unsigned short* __restrict__ Kb,   // [32,2048,128]
                 const unsigned short* __restrict__ Vtb,  // [32,32,128,64] tiled V^T
                 unsigned short* __restrict__ Ob) {       // [4096,2048]
  __shared__ alignas(16) unsigned short lds_all[33792];  // 66 KB
  unsigned short* Ks  = lds_all;           // [kv=64][d=128] swizzled, 16KB (single buf)
  unsigned short* Vs0 = lds_all + 8192;    // [d=128][kv=64] swizzled, 16KB
  unsigned short* Vs1 = lds_all + 16384;
  const int tid = threadIdx.x, lane = tid & 63, wave = tid >> 6;
  unsigned short* Ps = lds_all + 24576 + wave * (32 * PS_LD);
  const int quad = lane >> 4, l15 = lane & 15;
  const int bh = blockIdx.y;
  const int b = bh >> 4, h = bh & 15;
  const float c = 0.08838834764831845f * 1.4426950408889634f; // 1/sqrt(128)*log2(e)

  const unsigned short* Kbase = Kb + (size_t)bh * SEQ * DH;
  const unsigned short* Vbase = Vtb + (size_t)bh * 32 * 8192;

  for (int half = 0; half < 2; ++half) {
    const int qb = half ? (int)blockIdx.x : 15 - (int)blockIdx.x;
    const int q0 = qb * 128 + wave * 32;

    __syncthreads();   // lds_all free of previous pass's epilogue readers

    auto stage_k = [&](int kt) {
      const unsigned short* kg = Kbase + (size_t)kt * 64 * DH;
      #pragma unroll
      for (int r = 0; r < 4; ++r) {
        const int idx = r * 256 + tid;
        const int krow = idx >> 4, kchunk = (idx & 15) ^ (krow & 7);
        gl_lds16(kg + krow * DH + kchunk * 8, Ks + idx * 8);
      }
    };
    auto stage_v = [&](int kt, unsigned short* vs) {
      const unsigned short* vg = Vbase + (size_t)kt * 8192;
      #pragma unroll
      for (int r = 0; r < 4; ++r) {
        const int idx = r * 256 + tid;
        const int vrow = idx >> 3, vchunk = (idx & 7) ^ (vrow & 7);
        gl_lds16(vg + vrow * 64 + vchunk * 8, vs + idx * 8);
      }
    };

    // Q fragments in registers: A-layout m=lane&15, k=quad*8+j [m120]
    bf16x8 qf[2][4];
    #pragma unroll
    for (int mi = 0; mi < 2; ++mi)
      #pragma unroll
      for (int ds = 0; ds < 4; ++ds)
        qf[mi][ds] = *(const bf16x8*)(Qb + ((size_t)bh * SEQ + q0 + mi * 16 + l15) * DH + ds * 32 + quad * 8);

    f32x4 o[2][8];
    #pragma unroll
    for (int mi = 0; mi < 2; ++mi)
      #pragma unroll
      for (int di = 0; di < 8; ++di) o[mi][di] = (f32x4){0.f, 0.f, 0.f, 0.f};
    float m_i[2][4], l_i[2][4];
    #pragma unroll
    for (int mi = 0; mi < 2; ++mi)
      #pragma unroll
      for (int r = 0; r < 4; ++r) { m_i[mi][r] = -INFINITY; l_i[mi][r] = 0.f; }

    const int nkt = (qb + 1) * 2;   // 64-wide kv tiles (even, >=2)

    stage_v(0, Vs0);
    stage_k(0);
    __builtin_amdgcn_s_waitcnt(0x0F70);   // vmcnt(0)
    FENCE(); __builtin_amdgcn_s_barrier(); FENCE();

    for (int kt = 0; kt < nkt; ++kt) {
      unsigned short* Vcur = (kt & 1) ? Vs1 : Vs0;
      const bool more = (kt + 1 < nkt);
      if (more) stage_v(kt + 1, (kt & 1) ? Vs0 : Vs1);   // in flight during QK
      FENCE();

      // S = Q K^T from Ks
      f32x4 s_acc[2][4];
      #pragma unroll
      for (int mi = 0; mi < 2; ++mi)
        #pragma unroll
        for (int ni = 0; ni < 4; ++ni) s_acc[mi][ni] = (f32x4){0.f, 0.f, 0.f, 0.f};
      #pragma unroll
      for (int ds = 0; ds < 4; ++ds) {
        bf16x8 kf[4];
        #pragma unroll
        for (int ni = 0; ni < 4; ++ni) {
          const int krow = ni * 16 + l15;
          const int kc = (ds * 4 + quad) ^ (krow & 7);
          kf[ni] = *(const bf16x8*)(Ks + (krow * 16 + kc) * 8);
        }
        #pragma unroll
        for (int mi = 0; mi < 2; ++mi)
          #pragma unroll
          for (int ni = 0; ni < 4; ++ni)
            s_acc[mi][ni] = __builtin_amdgcn_mfma_f32_16x16x32_bf16(qf[mi][ds], kf[ni], s_acc[mi][ni], 0, 0, 0);
      }

      FENCE(); __builtin_amdgcn_s_barrier(); FENCE();  // all waves done reading Ks
      if (more) stage_k(kt + 1);                       // in flight during softmax+PV
      FENCE();

      // scale into 2^x domain (+ causal mask only on boundary tiles — wave-uniform)
      if (kt * 64 + 63 > q0) {
        #pragma unroll
        for (int mi = 0; mi < 2; ++mi)
          #pragma unroll
          for (int ni = 0; ni < 4; ++ni) {
            const int kcol = kt * 64 + ni * 16 + l15;
            #pragma unroll
            for (int r = 0; r < 4; ++r) {
              float v = s_acc[mi][ni][r] * c;
              const int qrow = q0 + mi * 16 + quad * 4 + r;
              if (kcol > qrow) v = -INFINITY;
              s_acc[mi][ni][r] = v;
            }
          }
      } else {
        #pragma unroll
        for (int mi = 0; mi < 2; ++mi)
          #pragma unroll
          for (int ni = 0; ni < 4; ++ni)
            #pragma unroll
            for (int r = 0; r < 4; ++r) s_acc[mi][ni][r] *= c;
      }

      // online softmax; row lives in its 16-lane group -> DPP rotate-reduce
      #pragma unroll
      for (int mi = 0; mi < 2; ++mi) {
        float rmax[4], alpha[4], rsum[4];
        #pragma unroll
        for (int r = 0; r < 4; ++r) {
          float m0 = fmaxf(fmaxf(s_acc[mi][0][r], s_acc[mi][1][r]),
                           fmaxf(s_acc[mi][2][r], s_acc[mi][3][r]));
          rmax[r] = red16_max(m0);
        }
        #pragma unroll
        for (int r = 0; r < 4; ++r) {
          const float mnew = fmaxf(m_i[mi][r], rmax[r]);
          alpha[r] = exp2f(m_i[mi][r] - mnew);   // exp2(-inf)=0 on first tile
          m_i[mi][r] = mnew;
        }
        #pragma unroll
        for (int r = 0; r < 4; ++r) {
          float s0 = 0.f;
          #pragma unroll
          for (int ni = 0; ni < 4; ++ni) {
            const float p = exp2f(s_acc[mi][ni][r] - m_i[mi][r]);
            s_acc[mi][ni][r] = p;
            s0 += p;
          }
          rsum[r] = red16_sum(s0);
        }
        #pragma unroll
        for (int r = 0; r < 4; ++r) l_i[mi][r] = l_i[mi][r] * alpha[r] + rsum[r];
        #pragma unroll
        for (int di = 0; di < 8; ++di)
          #pragma unroll
          for (int r = 0; r < 4; ++r) o[mi][di][r] *= alpha[r];
        // P: C-layout -> LDS (padded, per-wave private) -> A-layout [m120]
        #pragma unroll
        for (int ni = 0; ni < 4; ++ni)
          #pragma unroll
          for (int r = 0; r < 4; ++r)
            Ps[(mi * 16 + quad * 4 + r) * PS_LD + ni * 16 + l15] = f2bf(s_acc[mi][ni][r]);
      }
      FENCE();   // Ps ushort writes before bf16x8 reads (same-wave DS in-order)

      // O += P V from Vcur
      #pragma unroll
      for (int ks = 0; ks < 2; ++ks) {
        bf16x8 pf[2];
        #pragma unroll
        for (int mi = 0; mi < 2; ++mi)
          pf[mi] = *(const bf16x8*)(Ps + (mi * 16 + l15) * PS_LD + ks * 32 + quad * 8);
        #pragma unroll
        for (int di = 0; di < 8; ++di) {
          const int vrow = di * 16 + l15;
          const int vc = (ks * 4 + quad) ^ (vrow & 7);
          const bf16x8 vf = *(const bf16x8*)(Vcur + (vrow * 8 + vc) * 8);
          #pragma unroll
          for (int mi = 0; mi < 2; ++mi)
            o[mi][di] = __builtin_amdgcn_mfma_f32_16x16x32_bf16(pf[mi], vf, o[mi][di], 0, 0, 0);
        }
      }

      if (more) {
        __builtin_amdgcn_s_waitcnt(0x0F70);  // drain K(t+1)+V(t+1)
        FENCE(); __builtin_amdgcn_s_barrier(); FENCE();
      }
    }

    // ---- epilogue: normalize, transpose via LDS, coalesced 16B stores ----
    __syncthreads();   // all waves done with Vs/Ps before Osc overwrites lds_all
    {
      unsigned short* Osc = lds_all + wave * (32 * 136);   // max 17408 el < 33792
      #pragma unroll
      for (int mi = 0; mi < 2; ++mi) {
        float inv[4];
        #pragma unroll
        for (int r = 0; r < 4; ++r) inv[r] = 1.0f / l_i[mi][r];
        #pragma unroll
        for (int di = 0; di < 8; ++di)
          #pragma unroll
          for (int r = 0; r < 4; ++r)
            Osc[(mi * 16 + quad * 4 + r) * 136 + di * 16 + l15] = f2bf(o[mi][di][r] * inv[r]);
      }
      __syncthreads();                        // order writes before re-typed reads
      FENCE();
      #pragma unroll
      for (int rh = 0; rh < 2; ++rh)
        #pragma unroll
        for (int cg = 0; cg < 4; ++cg) {
          const int row = rh * 16 + (lane >> 2);
          const bf16x8 v8 = *(const bf16x8*)(Osc + row * 136 + cg * 32 + (lane & 3) * 8);
          *(bf16x8*)(Ob + ((size_t)(b * SEQ + q0 + row)) * DM + h * DH + cg * 32 + (lane & 3) * 8) = v8;
        }
    }
  }
}

// ---------------- out projection GEMM (m97 BK=32, unchanged) ----------------
__global__ void out_gemm_kernel(const unsigned short* __restrict__ A,   // [4096,2048] bf16
                                const unsigned short* __restrict__ Bt,  // [2048,2048] bf16 (W_out^T)
                                const float* __restrict__ bias,
                                float* __restrict__ out) {
  __shared__ alignas(16) unsigned short As[128 * 32];
  __shared__ alignas(16) unsigned short Bs[128 * 32];
  const int tid = threadIdx.x;
  const int lane = tid & 63, wave = tid >> 6;
  const int wm = wave >> 1, wn = wave & 1;
  const int quad = lane >> 4, l15 = lane & 15;
  const int bm = blockIdx.x, bn = blockIdx.y;
  const int K = DM;

  f32x4 acc[4][4];
  #pragma unroll
  for (int i = 0; i < 4; ++i)
    #pragma unroll
    for (int j = 0; j < 4; ++j) acc[i][j] = (f32x4){0.f, 0.f, 0.f, 0.f};

  const unsigned short* Ag = A + (size_t)(bm * 128 + (tid >> 2)) * K + (tid & 3) * 8;
  const unsigned short* Bg = Bt + (size_t)(bn * 128 + (tid >> 2)) * K + (tid & 3) * 8;

  for (int kt = 0; kt < K / 32; ++kt) {
    gl_lds16(Ag + kt * 32,                  As + tid * 8);
    gl_lds16(Ag + (size_t)64 * K + kt * 32, As + 2048 + tid * 8);
    gl_lds16(Bg + kt * 32,                  Bs + tid * 8);
    gl_lds16(Bg + (size_t)64 * K + kt * 32, Bs + 2048 + tid * 8);
    __syncthreads();
    bf16x8 af[4], bfr[4];
    #pragma unroll
    for (int mi = 0; mi < 4; ++mi)
      af[mi] = *(const bf16x8*)(As + (wm * 64 + mi * 16 + l15) * 32 + quad * 8);
    #pragma unroll
    for (int ni = 0; ni < 4; ++ni)
      bfr[ni] = *(const bf16x8*)(Bs + (wn * 64 + ni * 16 + l15) * 32 + quad * 8);
    #pragma unroll
    for (int mi = 0; mi < 4; ++mi)
      #pragma unroll
      for (int ni = 0; ni < 4; ++ni)
        acc[mi][ni] = __builtin_amdgcn_mfma_f32_16x16x32_bf16(af[mi], bfr[ni], acc[mi][ni], 0, 0, 0);
    __syncthreads();
  }

  #pragma unroll
  for (int mi = 0; mi < 4; ++mi) {
    #pragma unroll
    for (int ni = 0; ni < 4; ++ni) {
      const int grow0 = bm * 128 + wm * 64 + mi * 16 + quad * 4;
      const int gcol  = bn * 128 + wn * 64 + ni * 16 + l15;
      const float bv = bias[gcol];
      #pragma unroll
      for (int r = 0; r < 4; ++r)
        out[(size_t)(grow0 + r) * DM + gcol] = acc[mi][ni][r] + bv;
    }
  }
}

// ---------------- launch ----------------
extern "C" void kernel_launch(void* const* d_in, const int* in_sizes, int n_in,
                              void* d_out, int out_size, void* d_ws, size_t ws_size,
                              hipStream_t stream) {
  const float* x     = (const float*)d_in[0];   // [2,2048,2048]
  const float* W_qkv = (const float*)d_in[1];   // [2048,6144]
  const float* b_qkv = (const float*)d_in[2];   // [6144]
  const float* W_out = (const float*)d_in[3];   // [2048,2048]
  const float* b_out = (const float*)d_in[4];   // [2048]
  float* out = (float*)d_out;                   // [4096,2048]

  char* ws = (char*)d_ws;
  unsigned short* xb    = (unsigned short*)(ws);                 // 16 MB  [4096,2048]
  unsigned short* WqkvT = (unsigned short*)(ws + 16777216ull);   // 24 MB  [6144,2048]
  unsigned short* WoutT = (unsigned short*)(ws + 41943040ull);   //  8 MB  [2048,2048]
  unsigned short* Qb    = (unsigned short*)(ws + 50331648ull);   // 16 MB  [32,2048,128]
  unsigned short* Kb    = (unsigned short*)(ws + 67108864ull);   // 16 MB  [32,2048,128]
  unsigned short* Vtb   = (unsigned short*)(ws + 83886080ull);   // 16 MB  [32,32,128,64] tiled
  unsigned short* attnb = (unsigned short*)(ws + 100663296ull);  // 16 MB  [4096,2048]

  prep_kernel<<<dim3(24576), dim3(256), 0, stream>>>(x, W_qkv, W_out, xb, WqkvT, WoutT);
  qkv_gemm_kernel<<<dim3(32, 48), dim3(256), 0, stream>>>(xb, WqkvT, b_qkv, Qb, Kb, Vtb);
  attn_kernel<<<dim3(8, 32), dim3(256), 0, stream>>>(Qb, Kb, Vtb, attnb);
  out_gemm_kernel<<<dim3(32, 16), dim3(256), 0, stream>>>(attnb, WoutT, b_out, out);
}